// Round 1
// baseline (74.787 us; speedup 1.0000x reference)
//
#include <hip/hip_runtime.h>

// Haar DWT (single level), fp32.
// x: (8, 3, 1080, 1920)  ->  out: (8, 12, 540, 960)
// a=x[..,0::2,0::2] b=x[..,0::2,1::2] c=x[..,1::2,0::2] d=x[..,1::2,1::2], s=0.25
// ll=(a+b+c+d)s  lh=(a-b+c-d)s  hl=(a+b-c-d)s  hh=(a-b-c+d)s
// out channel layout: ch = c*4 + k, k in {ll,lh,hl,hh}

#define W_IN   1920
#define H_IN   1080
#define W2     960
#define H2     540
#define BC     24            // B*C = 8*3
#define WQ     (W2 / 4)      // 240: each thread does 4 output cols per band

__global__ __launch_bounds__(256) void haar_dwt_kernel(
    const float* __restrict__ x, float* __restrict__ out)
{
    const int total = BC * H2 * WQ;   // 3,110,400
    int tid = blockIdx.x * blockDim.x + threadIdx.x;
    if (tid >= total) return;

    int w  = tid % WQ;                // quad-column index: input cols [8w, 8w+8)
    int h  = (tid / WQ) % H2;         // output row -> input rows 2h, 2h+1
    int bc = tid / (WQ * H2);         // fused batch*channel, 0..23

    const size_t in_plane  = (size_t)H_IN * W_IN;
    const size_t out_plane = (size_t)H2 * W2;

    const float* top_p = x + (size_t)bc * in_plane + (size_t)(2 * h) * W_IN + 8 * w;
    const float* bot_p = top_p + W_IN;

    float4 t0 = reinterpret_cast<const float4*>(top_p)[0];
    float4 t1 = reinterpret_cast<const float4*>(top_p)[1];
    float4 b0 = reinterpret_cast<const float4*>(bot_p)[0];
    float4 b1 = reinterpret_cast<const float4*>(bot_p)[1];

    const float s = 0.25f;   // 0.5 / FACT, FACT = 2.0
    float4 ll, lh, hl, hh;

    // pixel 0: a=t0.x b=t0.y c=b0.x d=b0.y
    ll.x = (t0.x + t0.y + b0.x + b0.y) * s;
    lh.x = (t0.x - t0.y + b0.x - b0.y) * s;
    hl.x = (t0.x + t0.y - b0.x - b0.y) * s;
    hh.x = (t0.x - t0.y - b0.x + b0.y) * s;
    // pixel 1
    ll.y = (t0.z + t0.w + b0.z + b0.w) * s;
    lh.y = (t0.z - t0.w + b0.z - b0.w) * s;
    hl.y = (t0.z + t0.w - b0.z - b0.w) * s;
    hh.y = (t0.z - t0.w - b0.z + b0.w) * s;
    // pixel 2
    ll.z = (t1.x + t1.y + b1.x + b1.y) * s;
    lh.z = (t1.x - t1.y + b1.x - b1.y) * s;
    hl.z = (t1.x + t1.y - b1.x - b1.y) * s;
    hh.z = (t1.x - t1.y - b1.x + b1.y) * s;
    // pixel 3
    ll.w = (t1.z + t1.w + b1.z + b1.w) * s;
    lh.w = (t1.z - t1.w + b1.z - b1.w) * s;
    hl.w = (t1.z + t1.w - b1.z - b1.w) * s;
    hh.w = (t1.z - t1.w - b1.z + b1.w) * s;

    float* o = out + (size_t)(bc * 4) * out_plane + (size_t)h * W2 + 4 * w;
    reinterpret_cast<float4*>(o)[0]                 = ll;
    *reinterpret_cast<float4*>(o + out_plane)       = lh;
    *reinterpret_cast<float4*>(o + 2 * out_plane)   = hl;
    *reinterpret_cast<float4*>(o + 3 * out_plane)   = hh;
}

extern "C" void kernel_launch(void* const* d_in, const int* in_sizes, int n_in,
                              void* d_out, int out_size, void* d_ws, size_t ws_size,
                              hipStream_t stream) {
    const float* x = (const float*)d_in[0];
    float* out = (float*)d_out;

    const int total = BC * H2 * WQ;            // 3,110,400 threads
    const int block = 256;
    const int grid = (total + block - 1) / block;  // 12150
    haar_dwt_kernel<<<grid, block, 0, stream>>>(x, out);
}

// Round 3
// 72.892 us; speedup vs baseline: 1.0260x; 1.0260x over previous
//
#include <hip/hip_runtime.h>

// Haar DWT (single level), fp32.
// x: (8, 3, 1080, 1920)  ->  out: (8, 12, 540, 960)
// a=x[..,0::2,0::2] b=x[..,0::2,1::2] c=x[..,1::2,0::2] d=x[..,1::2,1::2], s=0.25
// ll=(a+b+c+d)s  lh=(a-b+c-d)s  hl=(a+b-c-d)s  hh=(a-b-c+d)s
// out channel layout: ch = c*4 + k, k in {ll,lh,hl,hh}
//
// R1/R2: nontemporal loads+stores (streaming, bypass L2 allocation) — data is
// read-once/write-once, 398 MB total >> 32 MB L2 aggregate. R2: use native
// ext_vector_type for the builtin (HIP float4 class is rejected).

#define W_IN   1920
#define H_IN   1080
#define W2     960
#define H2     540
#define BC     24            // B*C = 8*3
#define WQ     (W2 / 4)      // 240: each thread does 4 output cols per band

typedef float f32x4 __attribute__((ext_vector_type(4)));

__global__ __launch_bounds__(256) void haar_dwt_kernel(
    const float* __restrict__ x, float* __restrict__ out)
{
    const int total = BC * H2 * WQ;   // 3,110,400
    int tid = blockIdx.x * blockDim.x + threadIdx.x;
    if (tid >= total) return;

    int w  = tid % WQ;                // quad-column index: input cols [8w, 8w+8)
    int h  = (tid / WQ) % H2;         // output row -> input rows 2h, 2h+1
    int bc = tid / (WQ * H2);         // fused batch*channel, 0..23

    const size_t in_plane  = (size_t)H_IN * W_IN;
    const size_t out_plane = (size_t)H2 * W2;

    const float* top_p = x + (size_t)bc * in_plane + (size_t)(2 * h) * W_IN + 8 * w;
    const float* bot_p = top_p + W_IN;

    f32x4 t0 = __builtin_nontemporal_load(reinterpret_cast<const f32x4*>(top_p));
    f32x4 t1 = __builtin_nontemporal_load(reinterpret_cast<const f32x4*>(top_p) + 1);
    f32x4 b0 = __builtin_nontemporal_load(reinterpret_cast<const f32x4*>(bot_p));
    f32x4 b1 = __builtin_nontemporal_load(reinterpret_cast<const f32x4*>(bot_p) + 1);

    const float s = 0.25f;   // 0.5 / FACT, FACT = 2.0
    f32x4 ll, lh, hl, hh;

    // pixel 0: a=t0[0] b=t0[1] c=b0[0] d=b0[1]
    ll[0] = (t0[0] + t0[1] + b0[0] + b0[1]) * s;
    lh[0] = (t0[0] - t0[1] + b0[0] - b0[1]) * s;
    hl[0] = (t0[0] + t0[1] - b0[0] - b0[1]) * s;
    hh[0] = (t0[0] - t0[1] - b0[0] + b0[1]) * s;
    // pixel 1
    ll[1] = (t0[2] + t0[3] + b0[2] + b0[3]) * s;
    lh[1] = (t0[2] - t0[3] + b0[2] - b0[3]) * s;
    hl[1] = (t0[2] + t0[3] - b0[2] - b0[3]) * s;
    hh[1] = (t0[2] - t0[3] - b0[2] + b0[3]) * s;
    // pixel 2
    ll[2] = (t1[0] + t1[1] + b1[0] + b1[1]) * s;
    lh[2] = (t1[0] - t1[1] + b1[0] - b1[1]) * s;
    hl[2] = (t1[0] + t1[1] - b1[0] - b1[1]) * s;
    hh[2] = (t1[0] - t1[1] - b1[0] + b1[1]) * s;
    // pixel 3
    ll[3] = (t1[2] + t1[3] + b1[2] + b1[3]) * s;
    lh[3] = (t1[2] - t1[3] + b1[2] - b1[3]) * s;
    hl[3] = (t1[2] + t1[3] - b1[2] - b1[3]) * s;
    hh[3] = (t1[2] - t1[3] - b1[2] + b1[3]) * s;

    float* o = out + (size_t)(bc * 4) * out_plane + (size_t)h * W2 + 4 * w;
    __builtin_nontemporal_store(ll, reinterpret_cast<f32x4*>(o));
    __builtin_nontemporal_store(lh, reinterpret_cast<f32x4*>(o + out_plane));
    __builtin_nontemporal_store(hl, reinterpret_cast<f32x4*>(o + 2 * out_plane));
    __builtin_nontemporal_store(hh, reinterpret_cast<f32x4*>(o + 3 * out_plane));
}

extern "C" void kernel_launch(void* const* d_in, const int* in_sizes, int n_in,
                              void* d_out, int out_size, void* d_ws, size_t ws_size,
                              hipStream_t stream) {
    const float* x = (const float*)d_in[0];
    float* out = (float*)d_out;

    const int total = BC * H2 * WQ;            // 3,110,400 threads
    const int block = 256;
    const int grid = (total + block - 1) / block;  // 12150
    haar_dwt_kernel<<<grid, block, 0, stream>>>(x, out);
}

// Round 4
// 62.568 us; speedup vs baseline: 1.1953x; 1.1650x over previous
//
#include <hip/hip_runtime.h>

// Haar DWT (single level), fp32.
// x: (8, 3, 1080, 1920)  ->  out: (8, 12, 540, 960)
// a=x[..,0::2,0::2] b=x[..,0::2,1::2] c=x[..,1::2,0::2] d=x[..,1::2,1::2], s=0.25
// ll=(a+b+c+d)s  lh=(a-b+c-d)s  hl=(a+b-c-d)s  hh=(a-b-c+d)s
// out channel layout: ch = c*4 + k, k in {ll,lh,hl,hh}
//
// R3: NT stores ONLY (write-once stream, bypass L2 alloc). Loads are regular
// cached: per-instruction lane stride is 32B (half-density), and the L1 must
// serve the gap-filling partner load — NT loads defeated that in R2.

#define W_IN   1920
#define H_IN   1080
#define W2     960
#define H2     540
#define BC     24            // B*C = 8*3
#define WQ     (W2 / 4)      // 240: each thread does 4 output cols per band

typedef float f32x4 __attribute__((ext_vector_type(4)));

__global__ __launch_bounds__(256) void haar_dwt_kernel(
    const float* __restrict__ x, float* __restrict__ out)
{
    const int total = BC * H2 * WQ;   // 3,110,400
    int tid = blockIdx.x * blockDim.x + threadIdx.x;
    if (tid >= total) return;

    int w  = tid % WQ;                // quad-column index: input cols [8w, 8w+8)
    int h  = (tid / WQ) % H2;         // output row -> input rows 2h, 2h+1
    int bc = tid / (WQ * H2);         // fused batch*channel, 0..23

    const size_t in_plane  = (size_t)H_IN * W_IN;
    const size_t out_plane = (size_t)H2 * W2;

    const float* top_p = x + (size_t)bc * in_plane + (size_t)(2 * h) * W_IN + 8 * w;
    const float* bot_p = top_p + W_IN;

    f32x4 t0 = reinterpret_cast<const f32x4*>(top_p)[0];
    f32x4 t1 = reinterpret_cast<const f32x4*>(top_p)[1];
    f32x4 b0 = reinterpret_cast<const f32x4*>(bot_p)[0];
    f32x4 b1 = reinterpret_cast<const f32x4*>(bot_p)[1];

    const float s = 0.25f;   // 0.5 / FACT, FACT = 2.0
    f32x4 ll, lh, hl, hh;

    // pixel 0: a=t0[0] b=t0[1] c=b0[0] d=b0[1]
    ll[0] = (t0[0] + t0[1] + b0[0] + b0[1]) * s;
    lh[0] = (t0[0] - t0[1] + b0[0] - b0[1]) * s;
    hl[0] = (t0[0] + t0[1] - b0[0] - b0[1]) * s;
    hh[0] = (t0[0] - t0[1] - b0[0] + b0[1]) * s;
    // pixel 1
    ll[1] = (t0[2] + t0[3] + b0[2] + b0[3]) * s;
    lh[1] = (t0[2] - t0[3] + b0[2] - b0[3]) * s;
    hl[1] = (t0[2] + t0[3] - b0[2] - b0[3]) * s;
    hh[1] = (t0[2] - t0[3] - b0[2] + b0[3]) * s;
    // pixel 2
    ll[2] = (t1[0] + t1[1] + b1[0] + b1[1]) * s;
    lh[2] = (t1[0] - t1[1] + b1[0] - b1[1]) * s;
    hl[2] = (t1[0] + t1[1] - b1[0] - b1[1]) * s;
    hh[2] = (t1[0] - t1[1] - b1[0] + b1[1]) * s;
    // pixel 3
    ll[3] = (t1[2] + t1[3] + b1[2] + b1[3]) * s;
    lh[3] = (t1[2] - t1[3] + b1[2] - b1[3]) * s;
    hl[3] = (t1[2] + t1[3] - b1[2] - b1[3]) * s;
    hh[3] = (t1[2] - t1[3] - b1[2] + b1[3]) * s;

    float* o = out + (size_t)(bc * 4) * out_plane + (size_t)h * W2 + 4 * w;
    __builtin_nontemporal_store(ll, reinterpret_cast<f32x4*>(o));
    __builtin_nontemporal_store(lh, reinterpret_cast<f32x4*>(o + out_plane));
    __builtin_nontemporal_store(hl, reinterpret_cast<f32x4*>(o + 2 * out_plane));
    __builtin_nontemporal_store(hh, reinterpret_cast<f32x4*>(o + 3 * out_plane));
}

extern "C" void kernel_launch(void* const* d_in, const int* in_sizes, int n_in,
                              void* d_out, int out_size, void* d_ws, size_t ws_size,
                              hipStream_t stream) {
    const float* x = (const float*)d_in[0];
    float* out = (float*)d_out;

    const int total = BC * H2 * WQ;            // 3,110,400 threads
    const int block = 256;
    const int grid = (total + block - 1) / block;  // 12150
    haar_dwt_kernel<<<grid, block, 0, stream>>>(x, out);
}